// Round 4
// baseline (557.873 us; speedup 1.0000x reference)
//
#include <hip/hip_runtime.h>
#include <math.h>

// Contextual loss, N=1, C=256, H=W=96 -> S=9216.
// loss = log(S) - log( sum_j exp( -vcol_j ) )
//   vcol_j = min_i [ a_i * d_ij + ln S'_i ]
//   S'_i   = sum_j exp( -a_i * d_ij )
//   a_i    = 2 / (m_i + 1e-5),  m_i = min_j d_ij,  d = clip((1-cos)/2, 0)
// cos = Iv^T Tv; Iv,Tv bf16, stored transposed [S][C] (K-contiguous, NT GEMM).
// GEMM passes: full-K (64 KB) LDS staging per 128x128 tile via global_load_lds,
// one barrier pair per tile; A fragments register-resident per block.

typedef short v8s __attribute__((ext_vector_type(8)));
typedef float v4f __attribute__((ext_vector_type(4)));

static constexpr int Sn = 9216;
static constexpr int Cn = 256;

// ws float offsets
static constexpr size_t OFF_MEAN = 0;                      // 256 floats
static constexpr size_t OFF_MROW = 256;                    // Sn uint bits (row min d)
static constexpr size_t OFF_WROW = 256 + 9216;             // Sn floats (S'_i)
static constexpr size_t OFF_VCOL = 256 + 2 * 9216;         // Sn uint bits (col min v)
static constexpr size_t OFF_SUM  = 256 + 3 * 9216;         // 1 float
static constexpr size_t OFF_IV   = 32768;                  // Sn*Cn bf16
static constexpr size_t OFF_TV   = 32768 + (size_t)Sn * Cn / 2;

__device__ __forceinline__ unsigned bf16rne(float x) {
    unsigned u = __float_as_uint(x);
    return (u + 0x7FFFu + ((u >> 16) & 1u)) >> 16;
}

__device__ __forceinline__ void gload_lds16(const void* g, void* l) {
    __builtin_amdgcn_global_load_lds(
        (const __attribute__((address_space(1))) unsigned*)g,
        (__attribute__((address_space(3))) unsigned*)l, 16, 0, 0);
}

// ---------------- init ----------------
__global__ void k_init(float* ws) {
    int t = blockIdx.x * 256 + threadIdx.x;
    if (t < Sn) {
        ((unsigned*)(ws + OFF_MROW))[t] = 0x7F800000u;  // +inf
        ws[OFF_WROW + t] = 0.0f;
        ((unsigned*)(ws + OFF_VCOL))[t] = 0x7F800000u;  // +inf
    }
    if (t == 0) ws[OFF_SUM] = 0.0f;
}

// ---------------- per-channel mean of T ----------------
__global__ void k_mean(const float* __restrict__ T, float* ws) {
    __shared__ float red[256];
    int c = blockIdx.x;
    float s = 0.f;
    for (int i = threadIdx.x; i < Sn; i += 256) s += T[(size_t)c * Sn + i];
    red[threadIdx.x] = s;
    __syncthreads();
    for (int off = 128; off > 0; off >>= 1) {
        if (threadIdx.x < off) red[threadIdx.x] += red[threadIdx.x + off];
        __syncthreads();
    }
    if (threadIdx.x == 0) ws[OFF_MEAN + c] = red[0] * (1.0f / Sn);
}

// ------- center + L2 normalize along C, emit bf16 transposed [S][C] -------
// 144 blocks x 256 threads: 64 s-positions/block, 4 channel-quarters.
__global__ __launch_bounds__(256) void k_norm(const float* __restrict__ I,
                                              const float* __restrict__ T,
                                              float* ws) {
    __shared__ float mc[256];
    __shared__ float redI[4][64], redT[4][64];
    __shared__ float riS[64], rtS[64];
    const int tid = threadIdx.x, sl = tid & 63, cq = tid >> 6;
    const int s = blockIdx.x * 64 + sl;
    mc[tid] = ws[OFF_MEAN + tid];
    __syncthreads();
    float si = 0.f, st = 0.f;
    for (int c = cq * 64; c < cq * 64 + 64; ++c) {
        float xi = I[(size_t)c * Sn + s] - mc[c];
        float xt = T[(size_t)c * Sn + s] - mc[c];
        si += xi * xi;
        st += xt * xt;
    }
    redI[cq][sl] = si;
    redT[cq][sl] = st;
    __syncthreads();
    if (tid < 64) {
        float a = redI[0][tid] + redI[1][tid] + redI[2][tid] + redI[3][tid];
        float b = redT[0][tid] + redT[1][tid] + redT[2][tid] + redT[3][tid];
        riS[tid] = 1.0f / fmaxf(sqrtf(a), 1e-12f);
        rtS[tid] = 1.0f / fmaxf(sqrtf(b), 1e-12f);
    }
    __syncthreads();
    const float ri = riS[sl], rt = rtS[sl];
    unsigned short* Iv = (unsigned short*)(ws + OFF_IV);
    unsigned short* Tv = (unsigned short*)(ws + OFF_TV);
    uint4* Ivq = (uint4*)(Iv + (size_t)s * Cn);
    uint4* Tvq = (uint4*)(Tv + (size_t)s * Cn);
    for (int c8 = cq * 8; c8 < cq * 8 + 8; ++c8) {
        unsigned iw[4], tw[4];
#pragma unroll
        for (int h = 0; h < 4; ++h) {
            int c0 = c8 * 8 + 2 * h, c1 = c0 + 1;
            float i0 = (I[(size_t)c0 * Sn + s] - mc[c0]) * ri;
            float i1 = (I[(size_t)c1 * Sn + s] - mc[c1]) * ri;
            float t0 = (T[(size_t)c0 * Sn + s] - mc[c0]) * rt;
            float t1 = (T[(size_t)c1 * Sn + s] - mc[c1]) * rt;
            iw[h] = bf16rne(i0) | (bf16rne(i1) << 16);
            tw[h] = bf16rne(t0) | (bf16rne(t1) << 16);
        }
        Ivq[c8] = make_uint4(iw[0], iw[1], iw[2], iw[3]);
        Tvq[c8] = make_uint4(tw[0], tw[1], tw[2], tw[3]);
    }
}

// Stage 128 rows x 512 B (full K=256) into 64 KB LDS via global_load_lds.
// LDS: [row][32 phys chunks of 16B], phys p = logical c ^ (row & 15).
// Swizzle applied on global gather side (LDS dest = uniform base + lane*16).
__device__ __forceinline__ void stage_full(const char* Gb, char* lds, int tid) {
    const int lane = tid & 63, wave = tid >> 6;
    const int rsub = lane >> 5;     // 0/1: which row within the 1 KB wave write
    const int p = lane & 31;        // phys chunk
#pragma unroll
    for (int inst = 0; inst < 16; ++inst) {
        int rbase = wave * 32 + inst * 2;
        int r = rbase + rsub;
        int c = p ^ (r & 15);
        gload_lds16(Gb + (size_t)r * 512 + c * 16, lds + rbase * 512);
    }
}

// Load this wave's A fragments for K=256 into registers via LDS transit.
__device__ __forceinline__ void load_A_frags(const char* Ab, char* lds,
                                             int tid, v8s fa[4][8]) {
    const int lane = tid & 63, wave = tid >> 6;
    const int wm = wave >> 1, quad = (lane >> 4) & 3, l15 = lane & 15;
    stage_full(Ab, lds, tid);
    __syncthreads();
#pragma unroll
    for (int kc = 0; kc < 8; ++kc) {
        int p = (kc * 4 + quad) ^ l15;
#pragma unroll
        for (int mt = 0; mt < 4; ++mt) {
            int row = wm * 64 + mt * 16 + l15;
            fa[mt][kc] = *(const v8s*)(lds + row * 512 + p * 16);
        }
    }
}

// One 128x128 tile: stage full-K B through LDS (one barrier pair), MFMA
// against resident fa. acc must be pre-zeroed by caller.
__device__ __forceinline__ void tile_mma(const char* Bb, char* lds, int tid,
                                         const v8s fa[4][8], v4f acc[4][4]) {
    const int lane = tid & 63, wave = tid >> 6;
    const int wn = wave & 1, quad = (lane >> 4) & 3, l15 = lane & 15;
    __syncthreads();            // previous consumers of lds done
    stage_full(Bb, lds, tid);
    __syncthreads();            // staging drained
#pragma unroll
    for (int kc = 0; kc < 8; ++kc) {
        int p = (kc * 4 + quad) ^ l15;
#pragma unroll
        for (int nt = 0; nt < 4; ++nt) {
            int row = wn * 64 + nt * 16 + l15;
            v8s fb = *(const v8s*)(lds + row * 512 + p * 16);
#pragma unroll
            for (int mt = 0; mt < 4; ++mt)
                acc[mt][nt] = __builtin_amdgcn_mfma_f32_16x16x32_bf16(
                    fa[mt][kc], fb, acc[mt][nt], 0, 0, 0);
        }
    }
}

// ---------------- pass 1: m_i = min_j d_ij ----------------
__global__ __launch_bounds__(256, 2) void k_rowmin(float* ws) {
    __shared__ __align__(16) char Bsb[65536];
    const char* Ivb = (const char*)(ws + OFF_IV);
    const char* Tvb = (const char*)(ws + OFF_TV);
    const int tid = threadIdx.x, lane = tid & 63, wave = tid >> 6;
    const int wm = wave >> 1, quad = (lane >> 4) & 3, l15 = lane & 15;
    const int i0 = blockIdx.x * 128;
    v8s fa[4][8];
    load_A_frags(Ivb + (size_t)i0 * 512, Bsb, tid, fa);
    float mv[4][4];
#pragma unroll
    for (int mt = 0; mt < 4; ++mt)
#pragma unroll
        for (int r = 0; r < 4; ++r) mv[mt][r] = INFINITY;
    for (int t = 0; t < 9; ++t) {
        int j0 = (blockIdx.y * 9 + t) * 128;
        v4f acc[4][4];
#pragma unroll
        for (int mt = 0; mt < 4; ++mt)
#pragma unroll
            for (int nt = 0; nt < 4; ++nt)
#pragma unroll
                for (int r = 0; r < 4; ++r) acc[mt][nt][r] = 0.f;
        tile_mma(Tvb + (size_t)j0 * 512, Bsb, tid, fa, acc);
#pragma unroll
        for (int mt = 0; mt < 4; ++mt)
#pragma unroll
            for (int nt = 0; nt < 4; ++nt)
#pragma unroll
                for (int r = 0; r < 4; ++r) {
                    float d = fmaxf(0.5f - 0.5f * acc[mt][nt][r], 0.0f);
                    mv[mt][r] = fminf(mv[mt][r], d);
                }
    }
#pragma unroll
    for (int mt = 0; mt < 4; ++mt)
#pragma unroll
        for (int r = 0; r < 4; ++r) {
            float m = mv[mt][r];
            for (int off = 1; off < 16; off <<= 1)
                m = fminf(m, __shfl_xor(m, off, 64));
            if (l15 == 0)
                atomicMin((unsigned*)(ws + OFF_MROW) + i0 + wm * 64 + mt * 16 + quad * 4 + r,
                          __float_as_uint(m));
        }
}

// ---------------- pass 2: S'_i = sum_j exp(-a_i * d_ij) ----------------
__global__ __launch_bounds__(256, 2) void k_rowsum(float* ws) {
    __shared__ __align__(16) char Bsb[65536];
    const char* Ivb = (const char*)(ws + OFF_IV);
    const char* Tvb = (const char*)(ws + OFF_TV);
    const int tid = threadIdx.x, lane = tid & 63, wave = tid >> 6;
    const int wm = wave >> 1, quad = (lane >> 4) & 3, l15 = lane & 15;
    const int i0 = blockIdx.x * 128;
    v8s fa[4][8];
    load_A_frags(Ivb + (size_t)i0 * 512, Bsb, tid, fa);
    float c1[4][4], run[4][4];
#pragma unroll
    for (int mt = 0; mt < 4; ++mt)
#pragma unroll
        for (int r = 0; r < 4; ++r) {
            int i = i0 + wm * 64 + mt * 16 + quad * 4 + r;
            float mm = __uint_as_float(((unsigned*)(ws + OFF_MROW))[i]);
            c1[mt][r] = -1.4426950408889634f * 2.0f / (mm + 1e-5f);  // -a*log2e
            run[mt][r] = 0.f;
        }
    for (int t = 0; t < 9; ++t) {
        int j0 = (blockIdx.y * 9 + t) * 128;
        v4f acc[4][4];
#pragma unroll
        for (int mt = 0; mt < 4; ++mt)
#pragma unroll
            for (int nt = 0; nt < 4; ++nt)
#pragma unroll
                for (int r = 0; r < 4; ++r) acc[mt][nt][r] = 0.f;
        tile_mma(Tvb + (size_t)j0 * 512, Bsb, tid, fa, acc);
#pragma unroll
        for (int mt = 0; mt < 4; ++mt)
#pragma unroll
            for (int nt = 0; nt < 4; ++nt)
#pragma unroll
                for (int r = 0; r < 4; ++r) {
                    float d = fmaxf(0.5f - 0.5f * acc[mt][nt][r], 0.0f);
                    run[mt][r] += __builtin_amdgcn_exp2f(c1[mt][r] * d);
                }
    }
#pragma unroll
    for (int mt = 0; mt < 4; ++mt)
#pragma unroll
        for (int r = 0; r < 4; ++r) {
            float s = run[mt][r];
            for (int off = 1; off < 16; off <<= 1)
                s += __shfl_xor(s, off, 64);
            if (l15 == 0)
                atomicAdd(ws + OFF_WROW + i0 + wm * 64 + mt * 16 + quad * 4 + r, s);
        }
}

// ------- pass 3: vcol_j = min_i [ a_i * d_ij + ln S'_i ] -------------
// Rows of the tile = j (A from Tv), cols = i (B from Iv).
__global__ __launch_bounds__(256, 2) void k_colmin(float* ws) {
    __shared__ __align__(16) char Bsb[65536];
    const char* Ivb = (const char*)(ws + OFF_IV);
    const char* Tvb = (const char*)(ws + OFF_TV);
    const int tid = threadIdx.x, lane = tid & 63, wave = tid >> 6;
    const int wm = wave >> 1, wn = wave & 1, quad = (lane >> 4) & 3, l15 = lane & 15;
    const int j0 = blockIdx.x * 128;
    v8s fa[4][8];
    load_A_frags(Tvb + (size_t)j0 * 512, Bsb, tid, fa);
    float vmin[4][4];
#pragma unroll
    for (int mt = 0; mt < 4; ++mt)
#pragma unroll
        for (int r = 0; r < 4; ++r) vmin[mt][r] = INFINITY;
    for (int t = 0; t < 9; ++t) {
        int i0 = (blockIdx.y * 9 + t) * 128;
        v4f acc[4][4];
#pragma unroll
        for (int mt = 0; mt < 4; ++mt)
#pragma unroll
            for (int nt = 0; nt < 4; ++nt)
#pragma unroll
                for (int r = 0; r < 4; ++r) acc[mt][nt][r] = 0.f;
        tile_mma(Ivb + (size_t)i0 * 512, Bsb, tid, fa, acc);  // acc = cos[j][i]
#pragma unroll
        for (int nt = 0; nt < 4; ++nt) {
            int i = i0 + wn * 64 + nt * 16 + l15;
            float mm = __uint_as_float(((unsigned*)(ws + OFF_MROW))[i]);
            float a = 2.0f / (mm + 1e-5f);
            float lw = __builtin_amdgcn_logf(ws[OFF_WROW + i]) * 0.6931471805599453f;
#pragma unroll
            for (int mt = 0; mt < 4; ++mt)
#pragma unroll
                for (int r = 0; r < 4; ++r) {
                    float d = fmaxf(0.5f - 0.5f * acc[mt][nt][r], 0.0f);
                    vmin[mt][r] = fminf(vmin[mt][r], a * d + lw);
                }
        }
    }
#pragma unroll
    for (int mt = 0; mt < 4; ++mt)
#pragma unroll
        for (int r = 0; r < 4; ++r) {
            float v = vmin[mt][r];
            for (int off = 1; off < 16; off <<= 1)
                v = fminf(v, __shfl_xor(v, off, 64));
            if (l15 == 0)
                atomicMin((unsigned*)(ws + OFF_VCOL) + j0 + wm * 64 + mt * 16 + quad * 4 + r,
                          __float_as_uint(v));
        }
}

// ---------------- final: parallel sum then scalar write ----------------
__global__ void k_fsum(float* ws) {
    __shared__ float red[256];
    int j0 = blockIdx.x * 256 + threadIdx.x;
    float s = expf(-__uint_as_float(((const unsigned*)(ws + OFF_VCOL))[j0]));
    red[threadIdx.x] = s;
    __syncthreads();
    for (int off = 128; off > 0; off >>= 1) {
        if (threadIdx.x < off) red[threadIdx.x] += red[threadIdx.x + off];
        __syncthreads();
    }
    if (threadIdx.x == 0) atomicAdd(ws + OFF_SUM, red[0]);
}

__global__ void k_fwrite(const float* __restrict__ ws, float* __restrict__ out) {
    out[0] = logf((float)Sn) - logf(ws[OFF_SUM]);
}

extern "C" void kernel_launch(void* const* d_in, const int* in_sizes, int n_in,
                              void* d_out, int out_size, void* d_ws, size_t ws_size,
                              hipStream_t stream) {
    const float* I = (const float*)d_in[0];
    const float* T = (const float*)d_in[1];
    float* ws = (float*)d_ws;
    float* out = (float*)d_out;

    k_init<<<36, 256, 0, stream>>>(ws);
    k_mean<<<Cn, 256, 0, stream>>>(T, ws);
    k_norm<<<144, 256, 0, stream>>>(I, T, ws);
    k_rowmin<<<dim3(72, 8), 256, 0, stream>>>(ws);
    k_rowsum<<<dim3(72, 8), 256, 0, stream>>>(ws);
    k_colmin<<<dim3(72, 8), 256, 0, stream>>>(ws);
    k_fsum<<<36, 256, 0, stream>>>(ws);
    k_fwrite<<<1, 1, 0, stream>>>(ws, out);
}

// Round 5
// 328.593 us; speedup vs baseline: 1.6978x; 1.6978x over previous
//
#include <hip/hip_runtime.h>
#include <math.h>

// Contextual loss, N=1, C=256, H=W=96 -> S=9216.
// loss = log(S) - log( sum_j exp( -vcol_j ) )
//   vcol_j = min_i [ a_i * d_ij + ln S'_i ]   (== min_i a_i(d-m_i)+lnW_i >= 0)
//   S'_i   = sum_j exp( -a_i * d_ij )
//   a_i    = 2 / (m_i + 1e-5),  m_i = min_j d_ij,  d = clip((1-cos)/2, 0)
// Big-ws path: pass1 GEMM computes d once, stores fp16 D (170 MB) + rowmin;
// passes 2/3 are memory-bound streams over D. Small-ws fallback: 3 GEMMs.

typedef short v8s __attribute__((ext_vector_type(8)));
typedef float v4f __attribute__((ext_vector_type(4)));
typedef _Float16 v8h __attribute__((ext_vector_type(8)));

static constexpr int Sn = 9216;
static constexpr int Cn = 256;

// ws float offsets
static constexpr size_t OFF_MEAN = 0;                      // 256 floats
static constexpr size_t OFF_MROW = 256;                    // Sn uint bits (row min d)
static constexpr size_t OFF_WROW = 256 + 9216;             // Sn floats (S'_i)
static constexpr size_t OFF_VCOL = 256 + 2 * 9216;         // Sn uint bits (col min v)
static constexpr size_t OFF_SUM  = 256 + 3 * 9216;         // 1 float
static constexpr size_t OFF_IV   = 32768;                  // Sn*Cn bf16
static constexpr size_t OFF_TV   = 32768 + (size_t)Sn * Cn / 2;
static constexpr size_t OFF_ALW  = 32768 + (size_t)Sn * Cn;  // Sn float2 {a, lnS'}
static constexpr size_t OFF_D_B  = (size_t)16 << 20;       // byte offset of fp16 D
static constexpr size_t NEED_B   = OFF_D_B + (size_t)Sn * Sn * 2;  // ~187 MB

__device__ __forceinline__ unsigned bf16rne(float x) {
    unsigned u = __float_as_uint(x);
    return (u + 0x7FFFu + ((u >> 16) & 1u)) >> 16;
}

__device__ __forceinline__ void gload_lds16(const void* g, void* l) {
    __builtin_amdgcn_global_load_lds(
        (const __attribute__((address_space(1))) unsigned*)g,
        (__attribute__((address_space(3))) unsigned*)l, 16, 0, 0);
}

// ---------------- init ----------------
__global__ void k_init(float* ws) {
    int t = blockIdx.x * 256 + threadIdx.x;
    if (t < Sn) {
        ((unsigned*)(ws + OFF_MROW))[t] = 0x7F800000u;  // +inf
        ws[OFF_WROW + t] = 0.0f;
        ((unsigned*)(ws + OFF_VCOL))[t] = 0x7F800000u;  // +inf
    }
    if (t == 0) ws[OFF_SUM] = 0.0f;
}

// ---------------- per-channel mean of T ----------------
__global__ void k_mean(const float* __restrict__ T, float* ws) {
    __shared__ float red[256];
    int c = blockIdx.x;
    float s = 0.f;
    for (int i = threadIdx.x; i < Sn; i += 256) s += T[(size_t)c * Sn + i];
    red[threadIdx.x] = s;
    __syncthreads();
    for (int off = 128; off > 0; off >>= 1) {
        if (threadIdx.x < off) red[threadIdx.x] += red[threadIdx.x + off];
        __syncthreads();
    }
    if (threadIdx.x == 0) ws[OFF_MEAN + c] = red[0] * (1.0f / Sn);
}

// ------- center + L2 normalize along C, emit bf16 transposed [S][C] -------
__global__ __launch_bounds__(256) void k_norm(const float* __restrict__ I,
                                              const float* __restrict__ T,
                                              float* ws) {
    __shared__ float mc[256];
    __shared__ float redI[4][64], redT[4][64];
    __shared__ float riS[64], rtS[64];
    const int tid = threadIdx.x, sl = tid & 63, cq = tid >> 6;
    const int s = blockIdx.x * 64 + sl;
    mc[tid] = ws[OFF_MEAN + tid];
    __syncthreads();
    float si = 0.f, st = 0.f;
    for (int c = cq * 64; c < cq * 64 + 64; ++c) {
        float xi = I[(size_t)c * Sn + s] - mc[c];
        float xt = T[(size_t)c * Sn + s] - mc[c];
        si += xi * xi;
        st += xt * xt;
    }
    redI[cq][sl] = si;
    redT[cq][sl] = st;
    __syncthreads();
    if (tid < 64) {
        float a = redI[0][tid] + redI[1][tid] + redI[2][tid] + redI[3][tid];
        float b = redT[0][tid] + redT[1][tid] + redT[2][tid] + redT[3][tid];
        riS[tid] = 1.0f / fmaxf(sqrtf(a), 1e-12f);
        rtS[tid] = 1.0f / fmaxf(sqrtf(b), 1e-12f);
    }
    __syncthreads();
    const float ri = riS[sl], rt = rtS[sl];
    unsigned short* Iv = (unsigned short*)(ws + OFF_IV);
    unsigned short* Tv = (unsigned short*)(ws + OFF_TV);
    uint4* Ivq = (uint4*)(Iv + (size_t)s * Cn);
    uint4* Tvq = (uint4*)(Tv + (size_t)s * Cn);
    for (int c8 = cq * 8; c8 < cq * 8 + 8; ++c8) {
        unsigned iw[4], tw[4];
#pragma unroll
        for (int h = 0; h < 4; ++h) {
            int c0 = c8 * 8 + 2 * h, c1 = c0 + 1;
            float i0 = (I[(size_t)c0 * Sn + s] - mc[c0]) * ri;
            float i1 = (I[(size_t)c1 * Sn + s] - mc[c1]) * ri;
            float t0 = (T[(size_t)c0 * Sn + s] - mc[c0]) * rt;
            float t1 = (T[(size_t)c1 * Sn + s] - mc[c1]) * rt;
            iw[h] = bf16rne(i0) | (bf16rne(i1) << 16);
            tw[h] = bf16rne(t0) | (bf16rne(t1) << 16);
        }
        Ivq[c8] = make_uint4(iw[0], iw[1], iw[2], iw[3]);
        Tvq[c8] = make_uint4(tw[0], tw[1], tw[2], tw[3]);
    }
}

// ---- round-3 proven staging: 16 KB K-slices, 8-chunk XOR swizzle ----
__device__ __forceinline__ void stage_slice(const char* Gb, char* lds,
                                            int kcs, int tid) {
    const int lane = tid & 63, wave = tid >> 6;
#pragma unroll
    for (int w = 0; w < 4; ++w) {
        int gi = wave * 4 + w;
        int row = gi * 8 + (lane >> 3);
        int p = lane & 7;
        int c = p ^ (row & 7);
        const char* g = Gb + (size_t)row * 512 + kcs * 128 + c * 16;
        gload_lds16(g, lds + gi * 1024);
    }
}

__device__ __forceinline__ void load_A_frags(const char* Ab, char* lds,
                                             int tid, v8s fa[4][8]) {
    const int lane = tid & 63, wave = tid >> 6;
    const int wm = wave >> 1, quad = (lane >> 4) & 3, l15 = lane & 15;
#pragma unroll
    for (int kcs = 0; kcs < 4; ++kcs) {
        __syncthreads();
        stage_slice(Ab, lds, kcs, tid);
        __syncthreads();
#pragma unroll
        for (int ks = 0; ks < 2; ++ks) {
            int c = ks * 4 + quad;
#pragma unroll
            for (int mt = 0; mt < 4; ++mt) {
                int row = wm * 64 + mt * 16 + l15;
                int p = c ^ (row & 7);
                fa[mt][kcs * 2 + ks] = *(const v8s*)(lds + row * 128 + p * 16);
            }
        }
    }
}

__device__ __forceinline__ void tile_mma(const char* Bb, char* lds, int tid,
                                         const v8s fa[4][8], v4f acc[4][4]) {
    const int lane = tid & 63, wave = tid >> 6;
    const int wn = wave & 1, quad = (lane >> 4) & 3, l15 = lane & 15;
#pragma unroll
    for (int kc = 0; kc < 4; ++kc) {
        __syncthreads();
        stage_slice(Bb, lds, kc, tid);
        __syncthreads();
#pragma unroll
        for (int ks = 0; ks < 2; ++ks) {
            int c = ks * 4 + quad;
#pragma unroll
            for (int nt = 0; nt < 4; ++nt) {
                int row = wn * 64 + nt * 16 + l15;
                int p = c ^ (row & 7);
                v8s fb = *(const v8s*)(lds + row * 128 + p * 16);
#pragma unroll
                for (int mt = 0; mt < 4; ++mt)
                    acc[mt][nt] = __builtin_amdgcn_mfma_f32_16x16x32_bf16(
                        fa[mt][kc * 2 + ks], fb, acc[mt][nt], 0, 0, 0);
            }
        }
    }
}

// ======== BIG-WS PATH: pass 1 = GEMM + fp16 D store + rowmin ========
__global__ __launch_bounds__(256, 2) void k_gemm_d(float* ws) {
    __shared__ __align__(16) char Bsb[16384];
    const char* Ivb = (const char*)(ws + OFF_IV);
    const char* Tvb = (const char*)(ws + OFF_TV);
    _Float16* Dp = (_Float16*)((char*)ws + OFF_D_B);
    const int tid = threadIdx.x, lane = tid & 63, wave = tid >> 6;
    const int wm = wave >> 1, wn = wave & 1, quad = (lane >> 4) & 3, l15 = lane & 15;
    const int i0 = blockIdx.x * 128;
    v8s fa[4][8];
    load_A_frags(Ivb + (size_t)i0 * 512, Bsb, tid, fa);
    float mv[4][4];
#pragma unroll
    for (int mt = 0; mt < 4; ++mt)
#pragma unroll
        for (int r = 0; r < 4; ++r) mv[mt][r] = INFINITY;
    for (int t = 0; t < 9; ++t) {
        int j0 = (blockIdx.y * 9 + t) * 128;
        v4f acc[4][4];
#pragma unroll
        for (int mt = 0; mt < 4; ++mt)
#pragma unroll
            for (int nt = 0; nt < 4; ++nt)
#pragma unroll
                for (int r = 0; r < 4; ++r) acc[mt][nt][r] = 0.f;
        tile_mma(Tvb + (size_t)j0 * 512, Bsb, tid, fa, acc);
#pragma unroll
        for (int mt = 0; mt < 4; ++mt)
#pragma unroll
            for (int r = 0; r < 4; ++r) {
                int row = i0 + wm * 64 + mt * 16 + quad * 4 + r;
                _Float16* Drow = Dp + (size_t)row * Sn + j0 + wn * 64 + l15;
#pragma unroll
                for (int nt = 0; nt < 4; ++nt) {
                    float d = fmaxf(0.5f - 0.5f * acc[mt][nt][r], 0.0f);
                    mv[mt][r] = fminf(mv[mt][r], d);
                    Drow[nt * 16] = (_Float16)d;
                }
            }
    }
#pragma unroll
    for (int mt = 0; mt < 4; ++mt)
#pragma unroll
        for (int r = 0; r < 4; ++r) {
            float m = mv[mt][r];
            for (int off = 1; off < 16; off <<= 1)
                m = fminf(m, __shfl_xor(m, off, 64));
            if (l15 == 0)
                atomicMin((unsigned*)(ws + OFF_MROW) + i0 + wm * 64 + mt * 16 + quad * 4 + r,
                          __float_as_uint(m));
        }
}

// pass 2 (stream): S'_i = sum_j exp(-a_i d_ij).  grid (72, 9).
__global__ __launch_bounds__(256) void k_rowsum_d(float* ws) {
    const _Float16* Dp = (const _Float16*)((const char*)ws + OFF_D_B);
    const int tid = threadIdx.x, lane = tid & 63, wave = tid >> 6;
    const int i0 = blockIdx.x * 128 + wave * 32;
    const int j0 = blockIdx.y * 1024;
    for (int rr = 0; rr < 32; rr += 2) {
#pragma unroll
        for (int u = 0; u < 2; ++u) {
            int i = i0 + rr + u;
            float mm = __uint_as_float(((unsigned*)(ws + OFF_MROW))[i]);
            float c1 = -1.4426950408889634f * 2.0f / (mm + 1e-5f);
            const v8h* rowp = (const v8h*)(Dp + (size_t)i * Sn + j0);
            v8h h0 = rowp[lane * 2];
            v8h h1 = rowp[lane * 2 + 1];
            float s = 0.f;
#pragma unroll
            for (int k = 0; k < 8; ++k) {
                s += __builtin_amdgcn_exp2f(c1 * (float)h0[k]);
                s += __builtin_amdgcn_exp2f(c1 * (float)h1[k]);
            }
            for (int off = 1; off < 64; off <<= 1) s += __shfl_xor(s, off, 64);
            if (lane == 0) atomicAdd(ws + OFF_WROW + i, s);
        }
    }
}

// prep: {a_i, lnS'_i} as float2
__global__ void k_prep(float* ws) {
    int i = blockIdx.x * 256 + threadIdx.x;
    float mm = __uint_as_float(((unsigned*)(ws + OFF_MROW))[i]);
    float a = 2.0f / (mm + 1e-5f);
    float lw = logf(ws[OFF_WROW + i]);
    ((float2*)(ws + OFF_ALW))[i] = make_float2(a, lw);
}

// pass 3 (stream): vcol_j = min_i [a_i d_ij + lnS'_i].  grid (36, 18).
__global__ __launch_bounds__(256) void k_colmin_d(float* ws) {
    const _Float16* Dp = (const _Float16*)((const char*)ws + OFF_D_B);
    const float2* alw = (const float2*)(ws + OFF_ALW);
    const int j = blockIdx.x * 256 + threadIdx.x;
    const int i0 = blockIdx.y * 512;
    float vmin = INFINITY;
    for (int ii = 0; ii < 512; ii += 8) {
        float h[8];
        float2 al[8];
#pragma unroll
        for (int k = 0; k < 8; ++k) {
            int i = i0 + ii + k;
            h[k] = (float)Dp[(size_t)i * Sn + j];
            al[k] = alw[i];
        }
#pragma unroll
        for (int k = 0; k < 8; ++k)
            vmin = fminf(vmin, al[k].x * h[k] + al[k].y);
    }
    vmin = fmaxf(vmin, 0.0f);  // keep positive-bit atomicMin valid vs fp16 jitter
    atomicMin((unsigned*)(ws + OFF_VCOL) + j, __float_as_uint(vmin));
}

// ======== FALLBACK PATH (small ws): round-3 3-GEMM kernels ========
__global__ __launch_bounds__(256, 2) void k_rowmin(float* ws) {
    __shared__ __align__(16) char Bsb[16384];
    const char* Ivb = (const char*)(ws + OFF_IV);
    const char* Tvb = (const char*)(ws + OFF_TV);
    const int tid = threadIdx.x, lane = tid & 63, wave = tid >> 6;
    const int wm = wave >> 1, quad = (lane >> 4) & 3, l15 = lane & 15;
    const int i0 = blockIdx.x * 128;
    v8s fa[4][8];
    load_A_frags(Ivb + (size_t)i0 * 512, Bsb, tid, fa);
    float mv[4][4];
#pragma unroll
    for (int mt = 0; mt < 4; ++mt)
#pragma unroll
        for (int r = 0; r < 4; ++r) mv[mt][r] = INFINITY;
    for (int t = 0; t < 9; ++t) {
        int j0 = (blockIdx.y * 9 + t) * 128;
        v4f acc[4][4];
#pragma unroll
        for (int mt = 0; mt < 4; ++mt)
#pragma unroll
            for (int nt = 0; nt < 4; ++nt)
#pragma unroll
                for (int r = 0; r < 4; ++r) acc[mt][nt][r] = 0.f;
        tile_mma(Tvb + (size_t)j0 * 512, Bsb, tid, fa, acc);
#pragma unroll
        for (int mt = 0; mt < 4; ++mt)
#pragma unroll
            for (int nt = 0; nt < 4; ++nt)
#pragma unroll
                for (int r = 0; r < 4; ++r) {
                    float d = fmaxf(0.5f - 0.5f * acc[mt][nt][r], 0.0f);
                    mv[mt][r] = fminf(mv[mt][r], d);
                }
    }
#pragma unroll
    for (int mt = 0; mt < 4; ++mt)
#pragma unroll
        for (int r = 0; r < 4; ++r) {
            float m = mv[mt][r];
            for (int off = 1; off < 16; off <<= 1)
                m = fminf(m, __shfl_xor(m, off, 64));
            if (l15 == 0)
                atomicMin((unsigned*)(ws + OFF_MROW) + i0 + wm * 64 + mt * 16 + quad * 4 + r,
                          __float_as_uint(m));
        }
}

__global__ __launch_bounds__(256, 2) void k_rowsum(float* ws) {
    __shared__ __align__(16) char Bsb[16384];
    const char* Ivb = (const char*)(ws + OFF_IV);
    const char* Tvb = (const char*)(ws + OFF_TV);
    const int tid = threadIdx.x, lane = tid & 63, wave = tid >> 6;
    const int wm = wave >> 1, quad = (lane >> 4) & 3, l15 = lane & 15;
    const int i0 = blockIdx.x * 128;
    v8s fa[4][8];
    load_A_frags(Ivb + (size_t)i0 * 512, Bsb, tid, fa);
    float c1[4][4], run[4][4];
#pragma unroll
    for (int mt = 0; mt < 4; ++mt)
#pragma unroll
        for (int r = 0; r < 4; ++r) {
            int i = i0 + wm * 64 + mt * 16 + quad * 4 + r;
            float mm = __uint_as_float(((unsigned*)(ws + OFF_MROW))[i]);
            c1[mt][r] = -1.4426950408889634f * 2.0f / (mm + 1e-5f);
            run[mt][r] = 0.f;
        }
    for (int t = 0; t < 9; ++t) {
        int j0 = (blockIdx.y * 9 + t) * 128;
        v4f acc[4][4];
#pragma unroll
        for (int mt = 0; mt < 4; ++mt)
#pragma unroll
            for (int nt = 0; nt < 4; ++nt)
#pragma unroll
                for (int r = 0; r < 4; ++r) acc[mt][nt][r] = 0.f;
        tile_mma(Tvb + (size_t)j0 * 512, Bsb, tid, fa, acc);
#pragma unroll
        for (int mt = 0; mt < 4; ++mt)
#pragma unroll
            for (int nt = 0; nt < 4; ++nt)
#pragma unroll
                for (int r = 0; r < 4; ++r) {
                    float d = fmaxf(0.5f - 0.5f * acc[mt][nt][r], 0.0f);
                    run[mt][r] += __builtin_amdgcn_exp2f(c1[mt][r] * d);
                }
    }
#pragma unroll
    for (int mt = 0; mt < 4; ++mt)
#pragma unroll
        for (int r = 0; r < 4; ++r) {
            float s = run[mt][r];
            for (int off = 1; off < 16; off <<= 1)
                s += __shfl_xor(s, off, 64);
            if (l15 == 0)
                atomicAdd(ws + OFF_WROW + i0 + wm * 64 + mt * 16 + quad * 4 + r, s);
        }
}

__global__ __launch_bounds__(256, 2) void k_colmin(float* ws) {
    __shared__ __align__(16) char Bsb[16384];
    const char* Ivb = (const char*)(ws + OFF_IV);
    const char* Tvb = (const char*)(ws + OFF_TV);
    const int tid = threadIdx.x, lane = tid & 63, wave = tid >> 6;
    const int wm = wave >> 1, wn = wave & 1, quad = (lane >> 4) & 3, l15 = lane & 15;
    const int j0 = blockIdx.x * 128;
    v8s fa[4][8];
    load_A_frags(Tvb + (size_t)j0 * 512, Bsb, tid, fa);
    float vmin[4][4];
#pragma unroll
    for (int mt = 0; mt < 4; ++mt)
#pragma unroll
        for (int r = 0; r < 4; ++r) vmin[mt][r] = INFINITY;
    for (int t = 0; t < 9; ++t) {
        int i0 = (blockIdx.y * 9 + t) * 128;
        v4f acc[4][4];
#pragma unroll
        for (int mt = 0; mt < 4; ++mt)
#pragma unroll
            for (int nt = 0; nt < 4; ++nt)
#pragma unroll
                for (int r = 0; r < 4; ++r) acc[mt][nt][r] = 0.f;
        tile_mma(Ivb + (size_t)i0 * 512, Bsb, tid, fa, acc);
#pragma unroll
        for (int nt = 0; nt < 4; ++nt) {
            int i = i0 + wn * 64 + nt * 16 + l15;
            float mm = __uint_as_float(((unsigned*)(ws + OFF_MROW))[i]);
            float a = 2.0f / (mm + 1e-5f);
            float lw = __builtin_amdgcn_logf(ws[OFF_WROW + i]) * 0.6931471805599453f;
#pragma unroll
            for (int mt = 0; mt < 4; ++mt)
#pragma unroll
                for (int r = 0; r < 4; ++r) {
                    float d = fmaxf(0.5f - 0.5f * acc[mt][nt][r], 0.0f);
                    vmin[mt][r] = fminf(vmin[mt][r], a * d + lw);
                }
        }
    }
#pragma unroll
    for (int mt = 0; mt < 4; ++mt)
#pragma unroll
        for (int r = 0; r < 4; ++r) {
            float v = vmin[mt][r];
            for (int off = 1; off < 16; off <<= 1)
                v = fminf(v, __shfl_xor(v, off, 64));
            if (l15 == 0)
                atomicMin((unsigned*)(ws + OFF_VCOL) + j0 + wm * 64 + mt * 16 + quad * 4 + r,
                          __float_as_uint(v));
        }
}

// ---------------- final: parallel sum then scalar write ----------------
__global__ void k_fsum(float* ws) {
    __shared__ float red[256];
    int j0 = blockIdx.x * 256 + threadIdx.x;
    float s = expf(-__uint_as_float(((const unsigned*)(ws + OFF_VCOL))[j0]));
    red[threadIdx.x] = s;
    __syncthreads();
    for (int off = 128; off > 0; off >>= 1) {
        if (threadIdx.x < off) red[threadIdx.x] += red[threadIdx.x + off];
        __syncthreads();
    }
    if (threadIdx.x == 0) atomicAdd(ws + OFF_SUM, red[0]);
}

__global__ void k_fwrite(const float* __restrict__ ws, float* __restrict__ out) {
    out[0] = logf((float)Sn) - logf(ws[OFF_SUM]);
}

extern "C" void kernel_launch(void* const* d_in, const int* in_sizes, int n_in,
                              void* d_out, int out_size, void* d_ws, size_t ws_size,
                              hipStream_t stream) {
    const float* I = (const float*)d_in[0];
    const float* T = (const float*)d_in[1];
    float* ws = (float*)d_ws;
    float* out = (float*)d_out;

    k_init<<<36, 256, 0, stream>>>(ws);
    k_mean<<<Cn, 256, 0, stream>>>(T, ws);
    k_norm<<<144, 256, 0, stream>>>(I, T, ws);
    if (ws_size >= NEED_B) {
        k_gemm_d<<<dim3(72, 8), 256, 0, stream>>>(ws);
        k_rowsum_d<<<dim3(72, 9), 256, 0, stream>>>(ws);
        k_prep<<<36, 256, 0, stream>>>(ws);
        k_colmin_d<<<dim3(36, 18), 256, 0, stream>>>(ws);
    } else {
        k_rowmin<<<dim3(72, 8), 256, 0, stream>>>(ws);
        k_rowsum<<<dim3(72, 8), 256, 0, stream>>>(ws);
        k_colmin<<<dim3(72, 8), 256, 0, stream>>>(ws);
    }
    k_fsum<<<36, 256, 0, stream>>>(ws);
    k_fwrite<<<1, 1, 0, stream>>>(ws, out);
}